// Round 10
// baseline (506.968 us; speedup 1.0000x reference)
//
#include <hip/hip_runtime.h>
#include <hip/hip_bf16.h>

#define CIN 1024
#define HW2 9216
#define COUT 256
#define NSH 4
#define RHID 64
#define CPG 8
#define EPSV 1e-5f
#define GRPSZ (CPG * HW2)

typedef __attribute__((ext_vector_type(8))) short bf16x8;
typedef __attribute__((ext_vector_type(4))) float f32x4;

__device__ __forceinline__ unsigned short f2bf(float f) {
  unsigned u = __builtin_bit_cast(unsigned, f);
  u = (u + 0x7fffu + ((u >> 16) & 1u)) >> 16;
  return (unsigned short)u;
}
__device__ __forceinline__ float bf2f(unsigned short h) {
  unsigned u = (unsigned)h << 16;
  return __builtin_bit_cast(float, u);
}

// ---- kernel 1: feat -> bf16 panels (R6 format) + GAP partial sums ----------
// IDEMPOTENT (pure stores) so duplicate dispatches are legal.
__global__ __launch_bounds__(256) void k_prep(
    const float* __restrict__ feat, unsigned short* __restrict__ fbp,
    float* __restrict__ pooledpart) {
  __shared__ unsigned short T[512][36];
  const int seg = blockIdx.x, kq = blockIdx.y, b = blockIdx.z;
  const int tid = threadIdx.x, lane = tid & 63, w = tid >> 6;
  const int r = tid >> 3;          // k-row 0..31
  const int c8 = tid & 7;
  const float* f0 = feat + ((size_t)(b * CIN + kq * 32 + r)) * HW2 + seg * 512;
  float s = 0.f;
  #pragma unroll
  for (int p = 0; p < 16; ++p) {
    int n0 = (c8 + p * 8) * 4;
    float4 v = *(const float4*)(f0 + n0);
    s += v.x + v.y + v.z + v.w;
    T[n0][r]     = f2bf(v.x);
    T[n0 + 1][r] = f2bf(v.y);
    T[n0 + 2][r] = f2bf(v.z);
    T[n0 + 3][r] = f2bf(v.w);
  }
  s += __shfl_down(s, 4); s += __shfl_down(s, 2); s += __shfl_down(s, 1);
  if (c8 == 0)
    pooledpart[((size_t)(b * CIN + kq * 32 + r)) * 18 + seg] = s;
  __syncthreads();
  unsigned short* dbase = fbp + ((size_t)(b * 32 + kq) * 576 + seg * 32) * 512;
  const int n16 = lane >> 2;
  const int cc = (lane & 3) ^ (n16 & 3);
  #pragma unroll
  for (int i = 0; i < 8; ++i) {
    int np = i * 4 + w;
    int n = np * 16 + n16;
    uint2 lo = *(const uint2*)&T[n][cc * 8];
    uint2 hi = *(const uint2*)&T[n][cc * 8 + 4];
    uint4 o = make_uint4(lo.x, lo.y, hi.x, hi.y);
    *(uint4*)(dbase + (size_t)np * 512 + lane * 8) = o;
  }
}

// ---- kernel 1b: reduce 18 seg-partials -> pooled ---------------------------
__global__ __launch_bounds__(256) void k_red(
    const float* __restrict__ pooledpart, float* __restrict__ pooled) {
  int row = blockIdx.x * 256 + threadIdx.x;   // 8192
  const float* p = pooledpart + (size_t)row * 18;
  float s = 0.f;
  #pragma unroll
  for (int i = 0; i < 18; ++i) s += p[i];
  pooled[row] = s;
}

// ---- kernel 2a: SE mlp -> s[b][4] ------------------------------------------
__global__ __launch_bounds__(256) void k_se(
    const float* __restrict__ pooled, const float* __restrict__ w1,
    const float* __restrict__ b1, const float* __restrict__ w2,
    const float* __restrict__ b2, float* __restrict__ sg) {
  int b = blockIdx.x;
  int r = threadIdx.x & 63, q = threadIdx.x >> 6;
  const float* pp = pooled + b * CIN + q * 256;
  const float* wrow = w1 + (size_t)r * CIN + q * 256;
  float acc = 0.f;
  for (int c = 0; c < 256; ++c) acc += pp[c] * wrow[c];
  __shared__ float part[4][64];
  __shared__ float hid[64];
  part[q][r] = acc;
  __syncthreads();
  if (q == 0) {
    float h = (part[0][r] + part[1][r] + part[2][r] + part[3][r]) *
                  (1.f / (float)HW2) + b1[r];
    hid[r] = h > 0.f ? h : 0.f;
  }
  __syncthreads();
  if (threadIdx.x < NSH) {
    float a = 0.f;
    for (int k = 0; k < RHID; ++k) a += hid[k] * w2[threadIdx.x * RHID + k];
    a += b2[threadIdx.x];
    sg[b * NSH + threadIdx.x] = 1.f / (1.f + expf(-a));
  }
}

// ---- kernel 2b: conv_weight -> bf16; also zeroes stpart --------------------
__global__ __launch_bounds__(256) void k_cw(
    const float* __restrict__ w_red, const float* __restrict__ sg,
    unsigned short* __restrict__ cw, float* __restrict__ stpart) {
  if (blockIdx.x == 0) {
    stpart[threadIdx.x] = 0.f;
    stpart[256 + threadIdx.x] = 0.f;
  }
  int e4 = (blockIdx.x * 256 + threadIdx.x) * 4;
  int b = e4 >> 18;
  int rem = e4 & 262143;
  int i = rem & 1023;
  float sv = sg[b * NSH + (i >> 8)];
  float4 v = *(const float4*)(w_red + rem);
  ushort4 o;
  o.x = f2bf(v.x * sv); o.y = f2bf(v.y * sv);
  o.z = f2bf(v.z * sv); o.w = f2bf(v.w * sv);
  *(ushort4*)(cw + e4) = o;
}

// ---- kernel 3: batched GEMM (R9 verbatim) + fused stats --------------------
__device__ __forceinline__ void gl16(const void* g, void* l) {
  __builtin_amdgcn_global_load_lds(
      (const __attribute__((address_space(1))) unsigned int*)g,
      (__attribute__((address_space(3))) unsigned int*)l, 16, 0, 0);
}

__global__ __launch_bounds__(512, 4) void k_gemm(
    const unsigned short* __restrict__ fbp, const unsigned short* __restrict__ cw,
    unsigned short* __restrict__ xb, float* __restrict__ stpart) {
  __shared__ unsigned short As[256 * 32];  // [m][32k] linear
  __shared__ unsigned short Bs[128 * 32];  // 8 panels, pre-swizzled in global
  const int nt = blockIdx.x, b = blockIdx.y;
  const int p0 = nt * 128;
  const int tid = threadIdx.x, lane = tid & 63, w = tid >> 6;
  const int wr = w >> 1, wc = w & 1;
  const unsigned short* cwb = cw + (size_t)b * COUT * CIN;
  const unsigned short* bsrc = fbp + ((size_t)(b * 32) * 576 + nt * 8) * 512 +
                               tid * 8;

  f32x4 acc[4][4] = {};

  for (int kq = 0; kq < 32; ++kq) {
    __syncthreads();
    #pragma unroll
    for (int q = 0; q < 2; ++q) {
      int t = q * 512 + tid;
      gl16(cwb + (t >> 2) * CIN + kq * 32 + (t & 3) * 8,
           &As[(q * 512 + w * 64) * 8]);
    }
    gl16(bsrc + (size_t)kq * 294912, &Bs[(w * 64) * 8]);
    __syncthreads();

    bf16x8 af[4];
    #pragma unroll
    for (int mi = 0; mi < 4; ++mi) {
      int row = wr * 64 + mi * 16 + (lane & 15);
      af[mi] = *(const bf16x8*)&As[row * 32 + (lane >> 4) * 8];
    }
    bf16x8 bfv[4];
    #pragma unroll
    for (int ni = 0; ni < 4; ++ni) {
      int n = wc * 64 + ni * 16 + (lane & 15);
      bfv[ni] = *(const bf16x8*)&Bs[n * 32 + (((lane >> 4) ^ (n & 3)) * 8)];
    }
    #pragma unroll
    for (int mi = 0; mi < 4; ++mi)
      #pragma unroll
      for (int ni = 0; ni < 4; ++ni)
        acc[mi][ni] = __builtin_amdgcn_mfma_f32_16x16x32_bf16(
            af[mi], bfv[ni], acc[mi][ni], 0, 0, 0);
  }

  unsigned short* ob = xb + (size_t)b * COUT * HW2;
  #pragma unroll
  for (int mi = 0; mi < 4; ++mi) {
    int r0 = wr * 64 + mi * 16 + ((lane >> 4) << 2);
    #pragma unroll
    for (int ni = 0; ni < 4; ++ni) {
      int p = p0 + wc * 64 + ni * 16 + (lane & 15);
      #pragma unroll
      for (int j = 0; j < 4; ++j)
        ob[(size_t)(r0 + j) * HW2 + p] = f2bf(acc[mi][ni][j]);
    }
  }

  #pragma unroll
  for (int mi = 0; mi < 4; ++mi) {
    float s1 = 0.f, s2 = 0.f;
    #pragma unroll
    for (int ni = 0; ni < 4; ++ni)
      #pragma unroll
      for (int j = 0; j < 4; ++j) {
        float v = acc[mi][ni][j];
        s1 += v; s2 += v * v;
      }
    #pragma unroll
    for (int off = 1; off <= 16; off <<= 1) {
      s1 += __shfl_xor(s1, off);
      s2 += __shfl_xor(s2, off);
    }
    if ((lane & 31) == 0) {
      int g = 8 * wr + 2 * mi + (lane >> 5);
      atomicAdd(&stpart[(b * 32 + g) * 2], s1);
      atomicAdd(&stpart[(b * 32 + g) * 2 + 1], s2);
    }
  }
}

// ---- kernel 4: finalize stats ----------------------------------------------
__global__ __launch_bounds__(256) void k_fin(const float* __restrict__ stpart,
                                             float2* __restrict__ st) {
  int bg = threadIdx.x;
  float s1 = stpart[bg * 2], s2 = stpart[bg * 2 + 1];
  const float inv = 1.f / (float)GRPSZ;
  float mu = s1 * inv;
  float var = s2 * inv - mu * mu;
  st[bg] = make_float2(mu, rsqrtf(var + EPSV));
}

// ---- kernel 5: GN apply + ReLU (bf16 x -> fp32 out) ------------------------
__global__ __launch_bounds__(256) void k_apply(
    const unsigned short* __restrict__ xb, float* __restrict__ out,
    const float2* __restrict__ st, const float* __restrict__ gamma,
    const float* __restrict__ beta) {
  #pragma unroll
  for (int i = 0; i < 4; ++i) {
    unsigned e = ((unsigned)blockIdx.x * 1024 + i * 256 + threadIdx.x) * 4;
    unsigned row = (e >> 10) / 9;   // e / 9216
    int o = row & 255;
    float2 s = st[row >> 3];
    float g = gamma[o] * s.y;
    float bb = beta[o] - s.x * g;
    ushort4 v = *(const ushort4*)(xb + e);
    float4 r;
    r.x = fmaxf(bf2f(v.x) * g + bb, 0.f);
    r.y = fmaxf(bf2f(v.y) * g + bb, 0.f);
    r.z = fmaxf(bf2f(v.z) * g + bb, 0.f);
    r.w = fmaxf(bf2f(v.w) * g + bb, 0.f);
    *(float4*)(out + e) = r;
  }
}

extern "C" void kernel_launch(void* const* d_in, const int* in_sizes, int n_in,
                              void* d_out, int out_size, void* d_ws, size_t ws_size,
                              hipStream_t stream) {
  const float* feat  = (const float*)d_in[0];
  const float* w1    = (const float*)d_in[1];
  const float* b1    = (const float*)d_in[2];
  const float* w2    = (const float*)d_in[3];
  const float* b2    = (const float*)d_in[4];
  const float* w_red = (const float*)d_in[5];
  const float* gamma = (const float*)d_in[6];
  const float* beta  = (const float*)d_in[7];
  float* out = (float*)d_out;

  char* ws = (char*)d_ws;
  unsigned short* fbp = (unsigned short*)ws;                // 150,994,944 B
  unsigned short* cw  = (unsigned short*)(ws + 150994944);  //   4,194,304 B
  unsigned short* xbb = (unsigned short*)(ws + 155189248);  //  37,748,736 B
  float* pooledpart = (float*)(ws + 192937984);             //     589,824 B
  float* pooled = (float*)(ws + 193527808);                 //      32,768 B
  float* sg     = (float*)(ws + 193560576);                 //         128 B
  float* stpart = (float*)(ws + 193560704);                 //       2,048 B
  float2* st    = (float2*)(ws + 193562752);                //       2,048 B
  // diagnostic throwaways (never read):
  unsigned short* xb2 = (unsigned short*)(ws + 193564800);  //  37,748,736 B
  float* stpart2 = (float*)(ws + 231313536);                //       2,048 B

  // ---- real pipeline ----
  k_prep<<<dim3(18, 32, 8), 256, 0, stream>>>(feat, fbp, pooledpart);
  k_red<<<32, 256, 0, stream>>>(pooledpart, pooled);
  k_se<<<8, 256, 0, stream>>>(pooled, w1, b1, w2, b2, sg);
  k_cw<<<2048, 256, 0, stream>>>(w_red, sg, cw, stpart);
  k_gemm<<<dim3(72, 8), 512, 0, stream>>>(fbp, cw, xbb, stpart);
  k_fin<<<1, 256, 0, stream>>>(stpart, st);
  k_apply<<<4608, 256, 0, stream>>>(xbb, out, st, gamma, beta);
  // ---- diagnostic duplicates (idempotent / throwaway): ----
  // prep_dur = dur - 448.5us ; gemm_dur = 212.5us - prep_dur  (pre-registered)
  k_prep<<<dim3(18, 32, 8), 256, 0, stream>>>(feat, fbp, pooledpart);
  k_prep<<<dim3(18, 32, 8), 256, 0, stream>>>(feat, fbp, pooledpart);
  k_gemm<<<dim3(72, 8), 512, 0, stream>>>(fbp, cw, xb2, stpart2);
}

// Round 11
// 229.520 us; speedup vs baseline: 2.2088x; 2.2088x over previous
//
#include <hip/hip_runtime.h>
#include <hip/hip_bf16.h>

#define CIN 1024
#define HW2 9216
#define COUT 256
#define NSH 4
#define RHID 64
#define CPG 8
#define EPSV 1e-5f
#define GRPSZ (CPG * HW2)

typedef __attribute__((ext_vector_type(8))) short bf16x8;
typedef __attribute__((ext_vector_type(4))) float f32x4;

__device__ __forceinline__ unsigned short f2bf(float f) {
  unsigned u = __builtin_bit_cast(unsigned, f);
  u = (u + 0x7fffu + ((u >> 16) & 1u)) >> 16;
  return (unsigned short)u;
}
__device__ __forceinline__ float bf2f(unsigned short h) {
  unsigned u = (unsigned)h << 16;
  return __builtin_bit_cast(float, u);
}

// ---- kernel 1: feat -> bf16 panels + GAP partial sums ----------------------
// Panel: elem(b,kq,np,n16,k=8c+j) at ((b*32+kq)*576+np)*512 + n16*32 + slot*8+j
//   where slot = c ^ S(n16), S(n) = (n&3)^((n>>2)&3)   [2-way-free on read]
__global__ __launch_bounds__(256) void k_prep(
    const float* __restrict__ feat, unsigned short* __restrict__ fbp,
    float* __restrict__ pooledpart) {
  __shared__ unsigned short T[512][36];
  const int seg = blockIdx.x, kq = blockIdx.y, b = blockIdx.z;
  const int tid = threadIdx.x, lane = tid & 63, w = tid >> 6;
  const int r = tid >> 3;          // k-row 0..31
  const int c8 = tid & 7;
  const float* f0 = feat + ((size_t)(b * CIN + kq * 32 + r)) * HW2 + seg * 512;
  float s = 0.f;
  #pragma unroll
  for (int p = 0; p < 16; ++p) {
    int n0 = (c8 + p * 8) * 4;
    float4 v = *(const float4*)(f0 + n0);
    s += v.x + v.y + v.z + v.w;
    T[n0][r]     = f2bf(v.x);
    T[n0 + 1][r] = f2bf(v.y);
    T[n0 + 2][r] = f2bf(v.z);
    T[n0 + 3][r] = f2bf(v.w);
  }
  s += __shfl_down(s, 4); s += __shfl_down(s, 2); s += __shfl_down(s, 1);
  if (c8 == 0)
    pooledpart[((size_t)(b * CIN + kq * 32 + r)) * 18 + seg] = s;
  __syncthreads();
  unsigned short* dbase = fbp + ((size_t)(b * 32 + kq) * 576 + seg * 32) * 512;
  const int n16 = lane >> 2;
  const int cc = (lane & 3) ^ ((n16 & 3) ^ ((n16 >> 2) & 3));  // src chunk
  #pragma unroll
  for (int i = 0; i < 8; ++i) {
    int np = i * 4 + w;
    int n = np * 16 + n16;
    uint2 lo = *(const uint2*)&T[n][cc * 8];
    uint2 hi = *(const uint2*)&T[n][cc * 8 + 4];
    uint4 o = make_uint4(lo.x, lo.y, hi.x, hi.y);
    *(uint4*)(dbase + (size_t)np * 512 + lane * 8) = o;
  }
}

// ---- kernel 1b: reduce 18 seg-partials -> pooled ---------------------------
__global__ __launch_bounds__(256) void k_red(
    const float* __restrict__ pooledpart, float* __restrict__ pooled) {
  int row = blockIdx.x * 256 + threadIdx.x;   // 8192
  const float* p = pooledpart + (size_t)row * 18;
  float s = 0.f;
  #pragma unroll
  for (int i = 0; i < 18; ++i) s += p[i];
  pooled[row] = s;
}

// ---- kernel 2a: SE mlp -> s[b][4] ------------------------------------------
__global__ __launch_bounds__(256) void k_se(
    const float* __restrict__ pooled, const float* __restrict__ w1,
    const float* __restrict__ b1, const float* __restrict__ w2,
    const float* __restrict__ b2, float* __restrict__ sg) {
  int b = blockIdx.x;
  int r = threadIdx.x & 63, q = threadIdx.x >> 6;
  const float* pp = pooled + b * CIN + q * 256;
  const float* wrow = w1 + (size_t)r * CIN + q * 256;
  float acc = 0.f;
  for (int c = 0; c < 256; ++c) acc += pp[c] * wrow[c];
  __shared__ float part[4][64];
  __shared__ float hid[64];
  part[q][r] = acc;
  __syncthreads();
  if (q == 0) {
    float h = (part[0][r] + part[1][r] + part[2][r] + part[3][r]) *
                  (1.f / (float)HW2) + b1[r];
    hid[r] = h > 0.f ? h : 0.f;
  }
  __syncthreads();
  if (threadIdx.x < NSH) {
    float a = 0.f;
    for (int k = 0; k < RHID; ++k) a += hid[k] * w2[threadIdx.x * RHID + k];
    a += b2[threadIdx.x];
    sg[b * NSH + threadIdx.x] = 1.f / (1.f + expf(-a));
  }
}

// ---- kernel 2b: conv_weight -> bf16; also zeroes stpart --------------------
__global__ __launch_bounds__(256) void k_cw(
    const float* __restrict__ w_red, const float* __restrict__ sg,
    unsigned short* __restrict__ cw, float* __restrict__ stpart) {
  if (blockIdx.x == 0) {
    stpart[threadIdx.x] = 0.f;
    stpart[256 + threadIdx.x] = 0.f;
  }
  int e4 = (blockIdx.x * 256 + threadIdx.x) * 4;
  int b = e4 >> 18;
  int rem = e4 & 262143;
  int i = rem & 1023;
  float sv = sg[b * NSH + (i >> 8)];
  float4 v = *(const float4*)(w_red + rem);
  ushort4 o;
  o.x = f2bf(v.x * sv); o.y = f2bf(v.y * sv);
  o.z = f2bf(v.z * sv); o.w = f2bf(v.w * sv);
  *(ushort4*)(cw + e4) = o;
}

// ---- kernel 3: batched GEMM, 2-phase static dbuf + T2 swizzles -------------
// BM=128, BN=128, BK=32; 256 thr = 4 waves (2M x 2N), wave tile 64x64.
// grid (72, 2, 8) = 1152 blocks, ~3 resident/CU.
__device__ __forceinline__ void gl16(const void* g, void* l) {
  __builtin_amdgcn_global_load_lds(
      (const __attribute__((address_space(1))) unsigned int*)g,
      (__attribute__((address_space(3))) unsigned int*)l, 16, 0, 0);
}

__global__ __launch_bounds__(256, 3) void k_gemm(
    const unsigned short* __restrict__ fbp, const unsigned short* __restrict__ cw,
    unsigned short* __restrict__ xb, float* __restrict__ stpart) {
  __shared__ unsigned short As0[128 * 32];   // 8 KB each, static names so the
  __shared__ unsigned short As1[128 * 32];   // compiler can alias-separate
  __shared__ unsigned short Bs0[128 * 32];   // ds_reads from in-flight gl16s
  __shared__ unsigned short Bs1[128 * 32];
  const int nt = blockIdx.x, mt = blockIdx.y, b = blockIdx.z;
  const int p0 = nt * 128;
  const int tid = threadIdx.x, lane = tid & 63, w = tid >> 6;
  const int wr = w >> 1, wc = w & 1;
  const unsigned short* cwb = cw + ((size_t)b * COUT + mt * 128) * CIN;
  const unsigned short* bsrc = fbp + ((size_t)(b * 32) * 576 + nt * 8) * 512 +
                               tid * 8;

  // A staging decode: chunk c = q*256+tid; row=c>>2; slot cl=c&3 holds source
  // chunk cl ^ K(row), K(row) = (row>>1)&3  [pre-swizzled source, m173]
  int aoff[2];
  #pragma unroll
  for (int q = 0; q < 2; ++q) {
    int c = q * 256 + tid;
    int row = c >> 2;
    aoff[q] = row * CIN + (((c & 3) ^ ((row >> 1) & 3)) * 8);
  }

  f32x4 acc[4][4] = {};

  auto STAGE = [&](unsigned short* Ad, unsigned short* Bd, int kq) {
    #pragma unroll
    for (int q = 0; q < 2; ++q)
      gl16(cwb + aoff[q] + kq * 32, &Ad[(q * 256 + w * 64) * 8]);
    #pragma unroll
    for (int q = 0; q < 2; ++q)
      gl16(bsrc + (size_t)kq * 294912 + q * 2048, &Bd[(q * 256 + w * 64) * 8]);
  };
  auto COMPUTE = [&](const unsigned short* Ac, const unsigned short* Bc) {
    bf16x8 af[4];
    #pragma unroll
    for (int mi = 0; mi < 4; ++mi) {
      int row = wr * 64 + mi * 16 + (lane & 15);
      af[mi] = *(const bf16x8*)&Ac[row * 32 +
                                   (((lane >> 4) ^ ((row >> 1) & 3)) * 8)];
    }
    bf16x8 bfv[4];
    #pragma unroll
    for (int ni = 0; ni < 4; ++ni) {
      int n = wc * 64 + ni * 16 + (lane & 15);
      int S = (n & 3) ^ ((n >> 2) & 3);
      bfv[ni] = *(const bf16x8*)&Bc[(n & 127) * 32 + (((lane >> 4) ^ S) * 8)];
    }
    #pragma unroll
    for (int mi = 0; mi < 4; ++mi)
      #pragma unroll
      for (int ni = 0; ni < 4; ++ni)
        acc[mi][ni] = __builtin_amdgcn_mfma_f32_16x16x32_bf16(
            af[mi], bfv[ni], acc[mi][ni], 0, 0, 0);
  };

  // ---- 2-phase pipeline: stage(next) issued BEFORE compute(cur); the
  // __syncthreads at iteration end is the single vmcnt(0)+barrier per step.
  STAGE(As0, Bs0, 0);
  __syncthreads();
  for (int kk = 0; kk < 15; ++kk) {
    STAGE(As1, Bs1, 2 * kk + 1);
    COMPUTE(As0, Bs0);
    __syncthreads();
    STAGE(As0, Bs0, 2 * kk + 2);
    COMPUTE(As1, Bs1);
    __syncthreads();
  }
  STAGE(As1, Bs1, 31);
  COMPUTE(As0, Bs0);     // kq = 30
  __syncthreads();
  COMPUTE(As1, Bs1);     // kq = 31

  // ---- C-write (bf16): col = lane&15, row = (lane>>4)*4 + j ----
  unsigned short* ob = xb + (size_t)b * COUT * HW2;
  #pragma unroll
  for (int mi = 0; mi < 4; ++mi) {
    int r0 = mt * 128 + wr * 64 + mi * 16 + ((lane >> 4) << 2);
    #pragma unroll
    for (int ni = 0; ni < 4; ++ni) {
      int p = p0 + wc * 64 + ni * 16 + (lane & 15);
      #pragma unroll
      for (int j = 0; j < 4; ++j)
        ob[(size_t)(r0 + j) * HW2 + p] = f2bf(acc[mi][ni][j]);
    }
  }

  // ---- fused GN partial stats: g = mt*16 + wr*8 + mi*2 + (lane>=32) ----
  #pragma unroll
  for (int mi = 0; mi < 4; ++mi) {
    float s1 = 0.f, s2 = 0.f;
    #pragma unroll
    for (int ni = 0; ni < 4; ++ni)
      #pragma unroll
      for (int j = 0; j < 4; ++j) {
        float v = acc[mi][ni][j];
        s1 += v; s2 += v * v;
      }
    #pragma unroll
    for (int off = 1; off <= 16; off <<= 1) {
      s1 += __shfl_xor(s1, off);
      s2 += __shfl_xor(s2, off);
    }
    if ((lane & 31) == 0) {
      int g = mt * 16 + wr * 8 + mi * 2 + (lane >> 5);
      atomicAdd(&stpart[(b * 32 + g) * 2], s1);
      atomicAdd(&stpart[(b * 32 + g) * 2 + 1], s2);
    }
  }
}

// ---- kernel 4: finalize stats ----------------------------------------------
__global__ __launch_bounds__(256) void k_fin(const float* __restrict__ stpart,
                                             float2* __restrict__ st) {
  int bg = threadIdx.x;
  float s1 = stpart[bg * 2], s2 = stpart[bg * 2 + 1];
  const float inv = 1.f / (float)GRPSZ;
  float mu = s1 * inv;
  float var = s2 * inv - mu * mu;
  st[bg] = make_float2(mu, rsqrtf(var + EPSV));
}

// ---- kernel 5: GN apply + ReLU (bf16 x -> fp32 out) ------------------------
__global__ __launch_bounds__(256) void k_apply(
    const unsigned short* __restrict__ xb, float* __restrict__ out,
    const float2* __restrict__ st, const float* __restrict__ gamma,
    const float* __restrict__ beta) {
  #pragma unroll
  for (int i = 0; i < 4; ++i) {
    unsigned e = ((unsigned)blockIdx.x * 1024 + i * 256 + threadIdx.x) * 4;
    unsigned row = (e >> 10) / 9;   // e / 9216
    int o = row & 255;
    float2 s = st[row >> 3];
    float g = gamma[o] * s.y;
    float bb = beta[o] - s.x * g;
    ushort4 v = *(const ushort4*)(xb + e);
    float4 r;
    r.x = fmaxf(bf2f(v.x) * g + bb, 0.f);
    r.y = fmaxf(bf2f(v.y) * g + bb, 0.f);
    r.z = fmaxf(bf2f(v.z) * g + bb, 0.f);
    r.w = fmaxf(bf2f(v.w) * g + bb, 0.f);
    *(float4*)(out + e) = r;
  }
}

extern "C" void kernel_launch(void* const* d_in, const int* in_sizes, int n_in,
                              void* d_out, int out_size, void* d_ws, size_t ws_size,
                              hipStream_t stream) {
  const float* feat  = (const float*)d_in[0];
  const float* w1    = (const float*)d_in[1];
  const float* b1    = (const float*)d_in[2];
  const float* w2    = (const float*)d_in[3];
  const float* b2    = (const float*)d_in[4];
  const float* w_red = (const float*)d_in[5];
  const float* gamma = (const float*)d_in[6];
  const float* beta  = (const float*)d_in[7];
  float* out = (float*)d_out;

  char* ws = (char*)d_ws;
  unsigned short* fbp = (unsigned short*)ws;                // 150,994,944 B
  unsigned short* cw  = (unsigned short*)(ws + 150994944);  //   4,194,304 B
  unsigned short* xbb = (unsigned short*)(ws + 155189248);  //  37,748,736 B
  float* pooledpart = (float*)(ws + 192937984);             //     589,824 B
  float* pooled = (float*)(ws + 193527808);                 //      32,768 B
  float* sg     = (float*)(ws + 193560576);                 //         128 B
  float* stpart = (float*)(ws + 193560704);                 //       2,048 B
  float2* st    = (float2*)(ws + 193562752);                //       2,048 B

  k_prep<<<dim3(18, 32, 8), 256, 0, stream>>>(feat, fbp, pooledpart);
  k_red<<<32, 256, 0, stream>>>(pooledpart, pooled);
  k_se<<<8, 256, 0, stream>>>(pooled, w1, b1, w2, b2, sg);
  k_cw<<<2048, 256, 0, stream>>>(w_red, sg, cw, stpart);
  k_gemm<<<dim3(72, 2, 8), 256, 0, stream>>>(fbp, cw, xbb, stpart);
  k_fin<<<1, 256, 0, stream>>>(stpart, st);
  k_apply<<<4608, 256, 0, stream>>>(xbb, out, st, gamma, beta);
}